// Round 8
// baseline (134.641 us; speedup 1.0000x reference)
//
#include <hip/hip_runtime.h>
#include <stdint.h>

#define WW 1024
#define HH 1024
#define NB 4
#define HW (HH * WW)
#define NPIX (NB * HW)        // 4194304
#define NT 4096               // 32x32 tiles per input
#define INVALID 0xFFFFFFFFu
#define RS 8                  // rows per open strip

// aux region (ws+37MB) — NO pre-zeroing, write-before-read each iteration:
//   mm  float2[1024] : per-strip (min,max)
//   fcs u64[2048]    : per-ccl-block (comp<<32)|fg
//   lks u32[2048]    : per-block border links
//   zt  u32[8]       : [0],[1] root0 flags; [2] ticket (zeroed by k_open2);
//                      [3] persistent nonce counter; [4] iteration nonce
//   cw  u64[8192]    : seam-pair claim words (atomicExch second-arriver)
//
// Claim protocol (wait-free): pair (A,A+k), k in {1,7,8,9}, word cw[A*4+j].
// Both participants exch their unique tag AFTER publishing descriptors
// (agent stores drained by the barrier's vmcnt(0) before the exch — the same
// store->drain->RMW visibility mechanism as the proven lks/ticket pattern).
// Second arriver (exch returns partner tag) processes the pair's seams;
// first (sees poison) skips. Exactly-once, no waiting, no scheduling
// assumptions. Stale-tag safety: ws re-poison clears tags; if ws were NOT
// re-poisoned, the zt[3] nonce increments and changes every tag.

__device__ __forceinline__ uint32_t aload32(const uint32_t* p) {
    return __hip_atomic_load(p, __ATOMIC_RELAXED, __HIP_MEMORY_SCOPE_AGENT);
}
__device__ __forceinline__ void astore32(uint32_t* p, uint32_t v) {
    __hip_atomic_store(p, v, __ATOMIC_RELAXED, __HIP_MEMORY_SCOPE_AGENT);
}
__device__ __forceinline__ unsigned long long ctag(uint32_t word, uint32_t side,
                                                   uint32_t nonce) {
    unsigned long long x = ((unsigned long long)nonce << 24)
                         ^ ((unsigned long long)word * 2u + side)
                         ^ 0xA5C3000000000000ull;
    return x * 0x9E3779B97F4A7C15ull + 0x0123456789ABCDEFull;
}

// ---- open strip: cross erode+dilate + per-strip min/max (core verified) ----
__device__ __forceinline__ void do_open_strip(const float* __restrict__ in,
                                              float* __restrict__ out,
                                              int strip, uint32_t* S,
                                              float2* __restrict__ mmslot) {
    int b  = strip >> 7;
    int y0 = (strip & 127) * RS;
    int t  = threadIdx.x;
    float* sx = (float*)S;
    float* sw = (float*)S + 2580;
    float* smin = (float*)S + 5160;
    float* smax = (float*)S + 5164;
    const float4* inb = (const float4*)(in + (size_t)b * HW);
    float4* outb      = (float4*)(out + (size_t)b * HW);

    float4 A[RS + 4];
    #pragma unroll
    for (int j = 0; j < RS + 4; j++) {
        int iy = y0 - 2 + j;
        if (iy >= 0 && iy < HH) A[j] = inb[iy * 256 + t];
        else A[j] = make_float4(1e10f, 1e10f, 1e10f, 1e10f);  // erosion pad
    }
    #pragma unroll
    for (int rr = 0; rr < RS + 2; rr++) { sx[rr * 258 + t + 1] = A[rr + 1].x; sw[rr * 258 + t + 1] = A[rr + 1].w; }
    if (t < RS + 2) { sw[t * 258 + 0] = 1e10f; sx[t * 258 + 257] = 1e10f; }
    __syncthreads();

    float4 E[RS + 2];
    #pragma unroll
    for (int rr = 0; rr < RS + 2; rr++) {
        int ey = y0 - 1 + rr;
        float lw = sw[rr * 258 + t], rw = sx[rr * 258 + t + 2];
        float4 v = A[rr + 1];
        float hx = fminf(fminf(lw, v.x), v.y);
        float hy = fminf(fminf(v.x, v.y), v.z);
        float hz = fminf(fminf(v.y, v.z), v.w);
        float hw = fminf(fminf(v.z, v.w), rw);
        float4 e;
        e.x = fminf(hx, fminf(A[rr].x, A[rr + 2].x));
        e.y = fminf(hy, fminf(A[rr].y, A[rr + 2].y));
        e.z = fminf(hz, fminf(A[rr].z, A[rr + 2].z));
        e.w = fminf(hw, fminf(A[rr].w, A[rr + 2].w));
        if (ey < 0 || ey >= HH) e = make_float4(-1e10f, -1e10f, -1e10f, -1e10f);
        E[rr] = e;
    }
    __syncthreads();

    #pragma unroll
    for (int d = 0; d < RS; d++) { sx[d * 258 + t + 1] = E[d + 1].x; sw[d * 258 + t + 1] = E[d + 1].w; }
    if (t < RS) { sw[t * 258 + 0] = -1e10f; sx[t * 258 + 257] = -1e10f; }
    __syncthreads();

    float lmin = __uint_as_float(0x7F800000u);
    float lmax = 0.0f;
    #pragma unroll
    for (int d = 0; d < RS; d++) {
        float lw = sw[d * 258 + t], rw = sx[d * 258 + t + 2];
        float4 v = E[d + 1];
        float hx = fmaxf(fmaxf(lw, v.x), v.y);
        float hy = fmaxf(fmaxf(v.x, v.y), v.z);
        float hz = fmaxf(fmaxf(v.y, v.z), v.w);
        float hw = fmaxf(fmaxf(v.z, v.w), rw);
        float4 o;
        o.x = fmaxf(hx, fmaxf(E[d].x, E[d + 2].x));
        o.y = fmaxf(hy, fmaxf(E[d].y, E[d + 2].y));
        o.z = fmaxf(hz, fmaxf(E[d].z, E[d + 2].z));
        o.w = fmaxf(hw, fmaxf(E[d].w, E[d + 2].w));
        outb[(y0 + d) * 256 + t] = o;
        lmin = fminf(lmin, fminf(fminf(o.x, o.y), fminf(o.z, o.w)));
        lmax = fmaxf(lmax, fmaxf(fmaxf(o.x, o.y), fmaxf(o.z, o.w)));
    }
    for (int off = 32; off > 0; off >>= 1) {
        lmin = fminf(lmin, __shfl_down(lmin, off));
        lmax = fmaxf(lmax, __shfl_down(lmax, off));
    }
    if ((t & 63) == 0) { smin[t >> 6] = lmin; smax[t >> 6] = lmax; }
    __syncthreads();
    if (t == 0) {
        float m0 = fminf(fminf(smin[0], smin[1]), fminf(smin[2], smin[3]));
        float m1 = fmaxf(fmaxf(smax[0], smax[1]), fmaxf(smax[2], smax[3]));
        *mmslot = make_float2(m0, m1);
    }
}

// exact binarize threshold: smallest float B with (B-mn)/denom >= 0.5;
// v >= B is then bitwise identical to the reference predicate for every v.
__device__ __forceinline__ float calc_thr(float mn, float mx) {
    float denom = (mx - mn) + 1e-10f;   // reference association order
    uint32_t lo = 0, hi = 0x7F800000u;
    while (lo < hi) {
        uint32_t mid = (lo + hi) >> 1;
        float q = (__uint_as_float(mid) - mn) / denom;  // IEEE f32 div
        if (q >= 0.5f) hi = mid; else lo = mid + 1;
    }
    return __uint_as_float(lo);
}

// ---------------- LDS union-find (wave-private region) ----------------------
__device__ __forceinline__ uint32_t lload(uint32_t* lp, uint32_t x) {
    return __hip_atomic_load(&lp[x], __ATOMIC_RELAXED, __HIP_MEMORY_SCOPE_WORKGROUP);
}
__device__ __forceinline__ uint32_t lfind(uint32_t* lp, uint32_t x) {
    uint32_t p = lload(lp, x);
    while (p != x) {
        uint32_t gp = lload(lp, p);
        if (gp != p)
            __hip_atomic_store(&lp[x], gp, __ATOMIC_RELAXED, __HIP_MEMORY_SCOPE_WORKGROUP);
        x = p; p = gp;
    }
    return x;
}
__device__ uint32_t lunion(uint32_t* lp, uint32_t a, uint32_t b) {
    uint32_t ra = lfind(lp, a), rb = lfind(lp, b);
    while (ra != rb) {
        uint32_t hi = ra > rb ? ra : rb;
        uint32_t lo = ra ^ rb ^ hi;
        uint32_t old = atomicCAS(&lp[lo], lo, hi);
        if (old == lo) return 1;  // killed exactly one root
        ra = lfind(lp, old);
        rb = lfind(lp, hi);
    }
    return 0;
}
__device__ __forceinline__ int run_len(uint32_t bits) {  // consecutive 1s from bit 0
    return (int)__builtin_ctzll(~(uint64_t)bits);
}

// ---- binarize + tile-local run CCL + compact border-node emit --------------
// RUN-index labels (row*16+run#): 512-entry LP/SM. Descriptor / parent-init /
// zt stores are AGENT scope (read by other blocks within the fused kernel).
__device__ void do_ccl_tile(const float* __restrict__ opened, uint8_t* __restrict__ desc,
                            uint32_t* __restrict__ parent, uint32_t* __restrict__ zt,
                            int bank, int tile, int L,
                            uint32_t* M, uint32_t* LP, uint32_t* SM,
                            float thr, uint32_t* pkslot) {
    int b  = tile >> 10;
    int tt = tile & 1023;
    int ty0 = (tt >> 5) << 5;
    int tx0 = (tt & 31) << 5;
    uint32_t base = (uint32_t)b * HW + (uint32_t)ty0 * WW + tx0;

    #pragma unroll
    for (int q = 0; q < 2; q++) {          // 512-entry LP/SM: 128 uint4 each
        uint32_t u = (uint32_t)L + 64u * q;
        ((uint4*)LP)[u] = make_uint4(4*u, 4*u+1, 4*u+2, 4*u+3);
        ((uint4*)SM)[u] = make_uint4(INVALID, INVALID, INVALID, INVALID);
    }

    // dense loads: lane L covers row (L>>3)+8q, cols (L&7)*4..+3
    int r8 = L >> 3, c8 = (L & 7) << 2;
    uint32_t fgcnt = 0;
    #pragma unroll
    for (int q = 0; q < 4; q++) {
        int rr = r8 + 8 * q;
        float4 v = *(const float4*)(opened + base + (uint32_t)rr * WW + c8);
        uint32_t pb = (v.x >= thr ? 1u : 0u) | (v.y >= thr ? 2u : 0u)
                    | (v.z >= thr ? 4u : 0u) | (v.w >= thr ? 8u : 0u);
        fgcnt += __popc(pb);
        uint32_t part = pb << c8;
        part |= __shfl_xor(part, 1, 8);
        part |= __shfl_xor(part, 2, 8);
        part |= __shfl_xor(part, 4, 8);
        if ((L & 7) == 0) M[rr] = part;
    }
    __syncthreads();

    // unions: lane owns half-row (r = L>>1, half h = L&1)
    int r = L >> 1, h = L & 1;
    uint32_t rowm = M[r];
    uint32_t fstarts = rowm & ~(rowm << 1);        // full-row run starts
    uint32_t halfsel = 0xFFFFu << (16 * h);
    uint32_t starts = fstarts & halfsel;
    uint32_t runs = __popc(starts);
    uint32_t links = 0;
    if (r > 0 && starts) {
        uint32_t up = M[r - 1];
        uint32_t upstarts = up & ~(up << 1);
        uint32_t w0 = starts;
        while (w0) {
            int lx = __builtin_ctz(w0); w0 &= w0 - 1;
            int e = lx + run_len(rowm >> lx) - 1;
            int lo = lx ? lx - 1 : 0;
            int hi = (e >= 31) ? 31 : e + 1;
            uint32_t hm = (hi == 31) ? 0xFFFFFFFFu : ((1u << (hi + 1)) - 1u);
            uint32_t w = up & hm & ~((1u << lo) - 1u);
            uint32_t repA = ((uint32_t)r << 4) + __popc(fstarts & ((2u << e) - 1u)) - 1u;
            while (w) {
                int xs = __builtin_ctz(w);
                int xe = xs + run_len(up >> xs) - 1;
                uint32_t repB = (((uint32_t)r - 1) << 4)
                              + __popc(upstarts & ((2u << xe) - 1u)) - 1u;
                links += lunion(LP, repA, repB);
                w = (xe >= 31) ? 0u : (w & ~((1u << (xe + 1)) - 1u));
            }
        }
    }
    __syncthreads();

    // pixel-0 / label-0: isolated fg singleton at pixel 0 (all nbrs intra-tile)
    if (tile == 0 && L == 0)
        astore32(&zt[bank], ((rowm & 1u) && !(rowm & 2u) && LP[0] == 0u) ? 1u : 0u);

    // border slot assignment: lane handles positions 2L, 2L+1
    uint32_t rk[2]; bool fgk[2];
    #pragma unroll
    for (int j = 0; j < 2; j++) {
        int k = 2 * L + j;
        int li = (k < 32) ? k
               : (k < 64) ? (31 * 32 + (k - 32))
               : (k < 96) ? ((k - 64) << 5)
                          : (((k - 96) << 5) + 31);
        int ly = li >> 5, lx = li & 31;
        uint32_t rm = M[ly];
        bool f = (rm >> lx) & 1u;
        fgk[j] = f;
        if (f) {
            int e = lx + run_len(rm >> lx) - 1;
            uint32_t rst = rm & ~(rm << 1);
            uint32_t lbl = ((uint32_t)ly << 4) + __popc(rst & ((2u << e) - 1u)) - 1u;
            rk[j] = lfind(LP, lbl);
            atomicMin(&SM[rk[j]], (uint32_t)k);
        }
    }
    __syncthreads();

    uint32_t nodebase = (uint32_t)tile << 7;
    uint32_t d2 = 0;
    #pragma unroll
    for (int j = 0; j < 2; j++) {
        int k = 2 * L + j;
        uint32_t sb = 0xFFu;
        if (fgk[j]) {
            uint32_t s = SM[rk[j]];
            sb = s;
            if (s == (uint32_t)k)
                astore32(&parent[nodebase + k], nodebase + k);  // canonical only (agent)
        }
        d2 |= sb << (8 * j);
    }
    uint32_t w2 = d2 | (__shfl_down(d2, 1) << 16);
    if ((L & 1) == 0)                                    // agent u32 desc store
        astore32((uint32_t*)desc + (((uint32_t)tile) << 5) + (L >> 1), w2);

    uint32_t pk = (fgcnt << 20) | (runs << 10) | links;
    for (int off = 32; off > 0; off >>= 1) pk += __shfl_down(pk, off);
    if (L == 0) *pkslot = pk;
    __syncthreads();
}

// ---------------- global union-find on compact nodes (device scope) ---------
__device__ __forceinline__ uint32_t pload(uint32_t* P, uint32_t x) {
    return __hip_atomic_load(&P[x], __ATOMIC_RELAXED, __HIP_MEMORY_SCOPE_AGENT);
}
__device__ __forceinline__ uint32_t uf_find(uint32_t* P, uint32_t x) {
    uint32_t p = pload(P, x);
    while (p != x) {
        uint32_t gp = pload(P, p);
        if (gp != p)
            __hip_atomic_store(&P[x], gp, __ATOMIC_RELAXED, __HIP_MEMORY_SCOPE_AGENT);
        x = p; p = gp;
    }
    return x;
}
__device__ uint32_t uf_union(uint32_t* P, uint32_t a, uint32_t b) {
    uint32_t ra = uf_find(P, a);
    uint32_t rb = uf_find(P, b);
    while (ra != rb) {
        uint32_t hi = ra > rb ? ra : rb;
        uint32_t lo = ra ^ rb ^ hi;
        uint32_t old = atomicCAS(&P[lo], lo, hi);
        if (old == lo) return 1;  // killed exactly one root
        ra = uf_find(P, old);
        rb = uf_find(P, hi);
    }
    return 0;
}

// ---------------- kernels ---------------------------------------------------
__global__ void k_open2(const float* __restrict__ img, const float* __restrict__ lab,
                        float* __restrict__ op0, float* __restrict__ op1,
                        float2* __restrict__ mm, uint32_t* __restrict__ zt) {
    __shared__ uint32_t S[5168];
    if (blockIdx.x == 0 && threadIdx.x == 0) {
        astore32(&zt[2], 0u);    // ticket for k_cclb (kernel boundary = visible)
        uint32_t n = __hip_atomic_fetch_add(&zt[3], 1u,
                                            __ATOMIC_RELAXED, __HIP_MEMORY_SCOPE_AGENT);
        astore32(&zt[4], n);     // iteration nonce for claim tags
    }
    int bank = blockIdx.x >> 9;
    do_open_strip(bank ? lab : img, bank ? op1 : op0,
                  blockIdx.x & 511, S, &mm[blockIdx.x]);
}

// Fused CCL + border. Seams partitioned exactly as the verified r6 set:
//   E seam of per-bank tile Q (txx<31):  Q=4a+{0,1,2} intra-block a;
//                                        Q=4a+3 via claim pair (a,a+1)
//   S seam of Q (tyy<31):                via claim pair (a,a+8)  [4 seams]
//   SE corner of Q (txx<31,tyy<31):      Q=4a+{0,1,2} via (a,a+8); Q=4a+3 via (a,a+9)
//   SW corner of Q (txx>0, tyy<31):      Q=4a+{1,2,3} via (a,a+8); Q=4a   via (a,a+7)
// Pair validity (function of a only — both sides compute identically):
//   k=1: a%8!=7 | k=8: (a&255)<248 | k=9: both | k=7: (a&255)<248 && a%8!=0
__global__ __launch_bounds__(256, 8) void k_cclb(
        const float* __restrict__ op0, const float* __restrict__ op1,
        uint8_t* __restrict__ d0, uint8_t* __restrict__ d1,
        uint32_t* __restrict__ p0, uint32_t* __restrict__ p1,
        const float2* __restrict__ mm,
        unsigned long long* __restrict__ fcs, uint32_t* __restrict__ lks,
        unsigned long long* __restrict__ cw, uint32_t* __restrict__ zt,
        float* __restrict__ out) {
    __shared__ __align__(16) uint32_t S[4240];
    __shared__ uint32_t wonA[8], slist[16], clist[16], nsc2[2], qn;
    __shared__ uint32_t SWK[6];
    __shared__ unsigned long long SB[8];
    __shared__ uint32_t SL[8];

    int bank = blockIdx.x >> 10;
    int wave = threadIdx.x >> 6, L = threadIdx.x & 63;
    uint8_t* desc = bank ? d1 : d0;
    uint32_t* parent = bank ? p1 : p0;

    // per-bank min/max from the 512 strip slots (kernel boundary vs k_open2)
    {
        const float2* mb = mm + (bank << 9);
        float2 u = mb[threadIdx.x];
        float2 v = mb[threadIdx.x + 256];
        float mn = fminf(u.x, v.x), mx = fmaxf(u.y, v.y);
        for (int off = 32; off > 0; off >>= 1) {
            mn = fminf(mn, __shfl_down(mn, off));
            mx = fmaxf(mx, __shfl_down(mx, off));
        }
        float* sf = (float*)(S + 4228);
        if (L == 0) { sf[wave] = mn; sf[4 + wave] = mx; }
    }
    __syncthreads();
    float* sf = (float*)(S + 4228);
    float mnA = fminf(fminf(sf[0], sf[1]), fminf(sf[2], sf[3]));
    float mxA = fmaxf(fmaxf(sf[4], sf[5]), fmaxf(sf[6], sf[7]));
    float thr = calc_thr(mnA, mxA);

    // ---- phase A: tile CCL (verified core; desc/parent/zt agent-scope) ----
    uint32_t* M = S + wave * 1056;    // M[32] | LP[512] | SM[512]
    int tile = ((blockIdx.x & 1023) << 2) + wave;
    do_ccl_tile(bank ? op1 : op0, desc, parent, zt, bank,
                tile, L, M, M + 32, M + 544, thr, &S[4224 + wave]);
    // (do_ccl_tile ends with __syncthreads: every wave's desc stores drained)
    if (threadIdx.x == 0) {
        uint32_t fg = 0, comp = 0;
        #pragma unroll
        for (int w = 0; w < 4; w++) {
            uint32_t pk = S[4224 + w];
            fg   += pk >> 20;
            comp += ((pk >> 10) & 1023u) - (pk & 1023u);
        }
        __hip_atomic_store(&fcs[blockIdx.x],
                           ((unsigned long long)comp << 32) | fg,
                           __ATOMIC_RELAXED, __HIP_MEMORY_SCOPE_AGENT);
    }

    // ---- wait-free pairwise claims (threads 0..7: 4 forward, 4 backward) ---
    if (threadIdx.x < 8) {
        int j = threadIdx.x & 3;
        bool fw = threadIdx.x < 4;
        int k = (j == 0) ? 1 : (j == 1) ? 7 : (j == 2) ? 8 : 9;
        long long A = fw ? (long long)blockIdx.x : (long long)blockIdx.x - k;
        uint32_t won = 0xFFFFFFFFu;
        if (A >= 0) {
            uint32_t Ar = (uint32_t)A;
            uint32_t a255 = Ar & 255u, a7 = Ar & 7u;
            bool valid = (k == 1) ? (a7 != 7u)
                       : (k == 7) ? ((a255 < 248u) && (a7 != 0u))
                       : (k == 8) ? (a255 < 248u)
                                  : ((a255 < 248u) && (a7 != 7u));
            if (valid) {
                uint32_t nonce = aload32(&zt[4]);
                uint32_t word = Ar * 4u + (uint32_t)j;
                unsigned long long my = ctag(word, fw ? 0u : 1u, nonce);
                unsigned long long ot = ctag(word, fw ? 1u : 0u, nonce);
                unsigned long long old = __hip_atomic_exchange(&cw[word], my,
                        __ATOMIC_RELAXED, __HIP_MEMORY_SCOPE_AGENT);
                if (old == ot) won = Ar;   // second arriver: both descs published
            }
        }
        wonA[threadIdx.x] = won;
    }
    if (threadIdx.x == 200) qn = 0;
    __syncthreads();

    // ---- build seam/corner work lists (thread 0; tiny) ----
    // slist entry: per-bank tile | 0x1000 if ROW(S)-seam; col seams type 0
    // clist entry: per-bank tile | 0x1000 if SW corner; SE corner type 0
    if (threadIdx.x == 0) {
        int ns = 0, nc = 0;
        uint32_t tb = (blockIdx.x & 1023u) << 2;
        slist[ns++] = tb + 0;              // intra E seams (txx<31 always)
        slist[ns++] = tb + 1;
        slist[ns++] = tb + 2;
        #pragma unroll
        for (int s = 0; s < 8; s++) {
            uint32_t A = wonA[s];
            if (A == 0xFFFFFFFFu) continue;
            uint32_t at = (A & 1023u) << 2;
            int j = s & 3;
            if (j == 0) slist[ns++] = at + 3;                              // k=1: E
            else if (j == 2) {                                             // k=8
                slist[ns++] = (at + 0) | 0x1000u;
                slist[ns++] = (at + 1) | 0x1000u;
                slist[ns++] = (at + 2) | 0x1000u;
                slist[ns++] = (at + 3) | 0x1000u;
                clist[nc++] = at + 0;  clist[nc++] = at + 1;  clist[nc++] = at + 2;   // SE
                clist[nc++] = (at + 1) | 0x1000u;  clist[nc++] = (at + 2) | 0x1000u;  // SW
                clist[nc++] = (at + 3) | 0x1000u;
            }
            else if (j == 3) clist[nc++] = at + 3;                         // k=9: SE
            else clist[nc++] = at | 0x1000u;                               // k=7: SW
        }
        nsc2[0] = (uint32_t)ns; nsc2[1] = (uint32_t)nc;
    }
    __syncthreads();

    // ---- phase B: seam pair-gen (verified dedup), queue in reused S ----
    unsigned long long* Q = (unsigned long long*)S;   // <=1264 pairs, 2048 cap
    uint32_t ns = nsc2[0], nc = nsc2[1];
    const uint32_t* d32 = (const uint32_t*)desc;
    for (uint32_t s0 = 0; s0 < ns; s0 += 8) {
        uint32_t s = s0 + (threadIdx.x >> 5);
        int x = threadIdx.x & 31;
        uint32_t sA = 0xFFu, t = 0xFFu, nQ = 0, nP = 0;
        bool act = (s < ns);
        if (act) {
            uint32_t e = slist[s];
            uint32_t Qt = e & 4095u;
            bool row = (e & 0x1000u) != 0;
            uint32_t Pt = row ? (Qt + 32u) : (Qt + 1u);
            nQ = Qt << 7; nP = Pt << 7;
            uint32_t ob = row ? (32u + (uint32_t)x) : (96u + (uint32_t)x);
            uint32_t wA = aload32(d32 + (Qt << 5) + (ob >> 2));
            sA = (wA >> ((ob & 3u) * 8u)) & 0xFFu;
            uint32_t pb = row ? (uint32_t)x : (64u + (uint32_t)x);
            uint32_t wB = aload32(d32 + (Pt << 5) + (pb >> 2));
            t = (wB >> ((pb & 3u) * 8u)) & 0xFFu;
        }
        uint32_t tp1  = __shfl(t,  L + 1);
        uint32_t tm1  = __shfl(t,  L - 1);
        uint32_t sAp1 = __shfl(sA, L + 1);
        uint32_t sAm1 = __shfl(sA, L - 1);
        if (act && sA != 0xFFu) {
            uint32_t a = nQ + sA;
            if (t != 0xFFu && !(x > 0 && sAm1 == sA && tm1 == t))
                Q[atomicAdd(&qn, 1u)] = ((unsigned long long)a << 32) | (nP + t);
            if (x < 31 && tp1 != 0xFFu && tp1 != t && sAp1 != sA)
                Q[atomicAdd(&qn, 1u)] = ((unsigned long long)a << 32) | (nP + tp1);
            if (x > 0 && tm1 != 0xFFu && tm1 != t && sAm1 != sA)
                Q[atomicAdd(&qn, 1u)] = ((unsigned long long)a << 32) | (nP + tm1);
        }
    }
    if (threadIdx.x < nc) {
        uint32_t e = clist[threadIdx.x];
        uint32_t Qt = e & 4095u;
        bool isSW = (e & 0x1000u) != 0;
        uint32_t Pt = isSW ? (Qt + 31u) : (Qt + 33u);
        uint32_t wA = aload32(d32 + (Qt << 5) + (isSW ? 8u : 15u));
        uint32_t sB = isSW ? (wA & 0xFFu) : ((wA >> 24) & 0xFFu);   // dQ[32] / dQ[63]
        uint32_t wB = aload32(d32 + (Pt << 5) + (isSW ? 7u : 0u));
        uint32_t sQ = isSW ? ((wB >> 24) & 0xFFu) : (wB & 0xFFu);   // dP[31] / dP[0]
        if (sB != 0xFFu && sQ != 0xFFu)
            Q[atomicAdd(&qn, 1u)] =
                ((unsigned long long)((Qt << 7) + sB) << 32) | ((Pt << 7) + sQ);
    }
    __syncthreads();

    // ---- rebalanced union phase: all 256 threads share the queue ----
    uint32_t n = qn;
    uint32_t links = 0;
    for (uint32_t i = threadIdx.x; i < n; i += 256) {
        unsigned long long q = Q[i];
        links += uf_union(parent, (uint32_t)(q >> 32), (uint32_t)q);
    }
    for (int off = 32; off > 0; off >>= 1) links += __shfl_down(links, off);
    if (L == 0) SWK[wave] = links;
    __syncthreads();
    if (threadIdx.x == 0) {
        uint32_t lk = SWK[0] + SWK[1] + SWK[2] + SWK[3];
        __hip_atomic_store(&lks[blockIdx.x], lk, __ATOMIC_RELAXED, __HIP_MEMORY_SCOPE_AGENT);
        asm volatile("s_waitcnt vmcnt(0)" ::: "memory");   // r3-proven pattern
        uint32_t old = __hip_atomic_fetch_add(&zt[2], 1u,
                                              __ATOMIC_RELAXED, __HIP_MEMORY_SCOPE_AGENT);
        SWK[4] = old;
    }
    __syncthreads();
    if (SWK[4] == 2047u) {   // last of 2048 blocks: fused final reduce
        unsigned long long a0 = 0, a1 = 0;
        uint32_t l0 = 0, l1 = 0;
        #pragma unroll
        for (int k = 0; k < 4; k++) {
            int i = (int)threadIdx.x + (k << 8);
            a0 += __hip_atomic_load(&fcs[i],        __ATOMIC_RELAXED, __HIP_MEMORY_SCOPE_AGENT);
            a1 += __hip_atomic_load(&fcs[1024 + i], __ATOMIC_RELAXED, __HIP_MEMORY_SCOPE_AGENT);
            l0 += aload32(&lks[i]);
            l1 += aload32(&lks[1024 + i]);
        }
        for (int off = 32; off > 0; off >>= 1) {
            a0 += __shfl_down(a0, off);
            a1 += __shfl_down(a1, off);
            l0 += __shfl_down(l0, off);
            l1 += __shfl_down(l1, off);
        }
        if (L == 0) { SB[wave] = a0; SB[4 + wave] = a1; SL[wave] = l0; SL[4 + wave] = l1; }
        __syncthreads();
        if (threadIdx.x == 0) {
            unsigned long long A0 = SB[0] + SB[1] + SB[2] + SB[3];
            unsigned long long A1 = SB[4] + SB[5] + SB[6] + SB[7];
            uint32_t gl0 = SL[0] + SL[1] + SL[2] + SL[3];
            uint32_t gl1 = SL[4] + SL[5] + SL[6] + SL[7];
            uint32_t nf0 = (uint32_t)A0, lc0 = (uint32_t)(A0 >> 32);
            uint32_t nf1 = (uint32_t)A1, lc1 = (uint32_t)(A1 >> 32);
            uint32_t z0 = aload32(&zt[0]);
            uint32_t z1 = aload32(&zt[1]);
            uint32_t comps0 = lc0 - gl0;
            uint32_t comps1 = lc1 - gl1;
            float ccs  = (float)(comps0 - z0 + ((nf0 < (uint32_t)NPIX || z0) ? 1u : 0u));
            float ccsg = (float)(comps1 - z1 + ((nf1 < (uint32_t)NPIX || z1) ? 1u : 0u));
            out[0] = fabsf(ccsg - ccs) / (float)nf1;   // all exact ints < 2^24
        }
    }
}

extern "C" void kernel_launch(void* const* d_in, const int* in_sizes, int n_in,
                              void* d_out, int out_size, void* d_ws, size_t ws_size,
                              hipStream_t stream) {
    const float* img = (const float*)d_in[0];
    const float* lab = (const float*)d_in[1];
    float* out = (float*)d_out;
    char* ws = (char*)d_ws;

    float*    op0 = (float*)ws;                                      // 16 MB
    float*    op1 = (float*)(ws + (size_t)16 * 1024 * 1024);         // 16 MB
    uint8_t*  d0  = (uint8_t*)(ws + (size_t)32 * 1024 * 1024);       // 512 KB
    uint8_t*  d1  = (uint8_t*)(ws + (size_t)32 * 1024 * 1024 + 512 * 1024);
    uint32_t* p0  = (uint32_t*)(ws + (size_t)33 * 1024 * 1024);      // 2 MB
    uint32_t* p1  = (uint32_t*)(ws + (size_t)35 * 1024 * 1024);      // 2 MB
    char*     aux = ws + (size_t)37 * 1024 * 1024;
    float2*   mm  = (float2*)aux;                                    // 8 KB
    unsigned long long* fcs = (unsigned long long*)(aux + 8192);     // 16 KB
    uint32_t* lks = (uint32_t*)(aux + 24576);                        // 8 KB
    uint32_t* zt  = (uint32_t*)(aux + 32768);                        // 32 B
    unsigned long long* cw  = (unsigned long long*)(aux + 40960);    // 64 KB

    k_open2<<<2 * NB * (HH / RS), 256, 0, stream>>>(img, lab, op0, op1, mm, zt);
    k_cclb<<<2 * NT / 4, 256, 0, stream>>>(op0, op1, d0, d1, p0, p1, mm,
                                           fcs, lks, cw, zt, out);
}

// Round 9
// 110.606 us; speedup vs baseline: 1.2173x; 1.2173x over previous
//
#include <hip/hip_runtime.h>
#include <stdint.h>

#define WW 1024
#define HH 1024
#define NB 4
#define HW (HH * WW)
#define NPIX (NB * HW)        // 4194304
#define NT 4096               // 32x32 tiles per input
#define INVALID 0xFFFFFFFFu
#define RS 8                  // rows per open strip

// aux region (ws+37MB) — NO pre-zeroing except gct/zt[2] (zeroed by k_open2
// block 0; kernel boundary makes it visible to k_cclb):
//   mm  float2[1024] : per-strip (min,max)
//   fcs u64[2048]    : per-ccl-block (comp<<32)|fg
//   lks u32[2048]    : per-block border links
//   zt  u32[8]       : [0],[1] root0 flags; [2] TOP ticket (64 group-lasts);
//                      [3] persistent nonce counter; [4] iteration nonce
//   gct u32[64]      : per-group (32 blocks) done counters  [hierarchical
//                      ticket: same-address RMW depth 2048 -> 64+64]
//   cw  u64[8192]    : seam-pair claim words (atomicExch second-arriver)

__device__ __forceinline__ uint32_t aload32(const uint32_t* p) {
    return __hip_atomic_load(p, __ATOMIC_RELAXED, __HIP_MEMORY_SCOPE_AGENT);
}
__device__ __forceinline__ void astore32(uint32_t* p, uint32_t v) {
    __hip_atomic_store(p, v, __ATOMIC_RELAXED, __HIP_MEMORY_SCOPE_AGENT);
}
__device__ __forceinline__ unsigned long long ctag(uint32_t word, uint32_t side,
                                                   uint32_t nonce) {
    unsigned long long x = ((unsigned long long)nonce << 24)
                         ^ ((unsigned long long)word * 2u + side)
                         ^ 0xA5C3000000000000ull;
    return x * 0x9E3779B97F4A7C15ull + 0x0123456789ABCDEFull;
}

// descriptor byte read: LDS if the tile belongs to this block, else agent load
__device__ __forceinline__ uint32_t read_desc_b(const uint32_t* d32,
        const uint16_t (*ownd)[64], uint32_t tb4, uint32_t tile, uint32_t bi) {
    if ((tile >> 2) == tb4) {
        uint16_t h = ownd[tile & 3u][bi >> 1];
        return (bi & 1u) ? ((uint32_t)(h >> 8) & 0xFFu) : ((uint32_t)h & 0xFFu);
    }
    uint32_t w = aload32(d32 + (tile << 5) + (bi >> 2));
    return (w >> ((bi & 3u) * 8u)) & 0xFFu;
}

// ---- open strip: cross erode+dilate + per-strip min/max (core verified) ----
__device__ __forceinline__ void do_open_strip(const float* __restrict__ in,
                                              float* __restrict__ out,
                                              int strip, uint32_t* S,
                                              float2* __restrict__ mmslot) {
    int b  = strip >> 7;
    int y0 = (strip & 127) * RS;
    int t  = threadIdx.x;
    float* sx = (float*)S;
    float* sw = (float*)S + 2580;
    float* smin = (float*)S + 5160;
    float* smax = (float*)S + 5164;
    const float4* inb = (const float4*)(in + (size_t)b * HW);
    float4* outb      = (float4*)(out + (size_t)b * HW);

    float4 A[RS + 4];
    #pragma unroll
    for (int j = 0; j < RS + 4; j++) {
        int iy = y0 - 2 + j;
        if (iy >= 0 && iy < HH) A[j] = inb[iy * 256 + t];
        else A[j] = make_float4(1e10f, 1e10f, 1e10f, 1e10f);  // erosion pad
    }
    #pragma unroll
    for (int rr = 0; rr < RS + 2; rr++) { sx[rr * 258 + t + 1] = A[rr + 1].x; sw[rr * 258 + t + 1] = A[rr + 1].w; }
    if (t < RS + 2) { sw[t * 258 + 0] = 1e10f; sx[t * 258 + 257] = 1e10f; }
    __syncthreads();

    float4 E[RS + 2];
    #pragma unroll
    for (int rr = 0; rr < RS + 2; rr++) {
        int ey = y0 - 1 + rr;
        float lw = sw[rr * 258 + t], rw = sx[rr * 258 + t + 2];
        float4 v = A[rr + 1];
        float hx = fminf(fminf(lw, v.x), v.y);
        float hy = fminf(fminf(v.x, v.y), v.z);
        float hz = fminf(fminf(v.y, v.z), v.w);
        float hw = fminf(fminf(v.z, v.w), rw);
        float4 e;
        e.x = fminf(hx, fminf(A[rr].x, A[rr + 2].x));
        e.y = fminf(hy, fminf(A[rr].y, A[rr + 2].y));
        e.z = fminf(hz, fminf(A[rr].z, A[rr + 2].z));
        e.w = fminf(hw, fminf(A[rr].w, A[rr + 2].w));
        if (ey < 0 || ey >= HH) e = make_float4(-1e10f, -1e10f, -1e10f, -1e10f);
        E[rr] = e;
    }
    __syncthreads();

    #pragma unroll
    for (int d = 0; d < RS; d++) { sx[d * 258 + t + 1] = E[d + 1].x; sw[d * 258 + t + 1] = E[d + 1].w; }
    if (t < RS) { sw[t * 258 + 0] = -1e10f; sx[t * 258 + 257] = -1e10f; }
    __syncthreads();

    float lmin = __uint_as_float(0x7F800000u);
    float lmax = 0.0f;
    #pragma unroll
    for (int d = 0; d < RS; d++) {
        float lw = sw[d * 258 + t], rw = sx[d * 258 + t + 2];
        float4 v = E[d + 1];
        float hx = fmaxf(fmaxf(lw, v.x), v.y);
        float hy = fmaxf(fmaxf(v.x, v.y), v.z);
        float hz = fmaxf(fmaxf(v.y, v.z), v.w);
        float hw = fmaxf(fmaxf(v.z, v.w), rw);
        float4 o;
        o.x = fmaxf(hx, fmaxf(E[d].x, E[d + 2].x));
        o.y = fmaxf(hy, fmaxf(E[d].y, E[d + 2].y));
        o.z = fmaxf(hz, fmaxf(E[d].z, E[d + 2].z));
        o.w = fmaxf(hw, fmaxf(E[d].w, E[d + 2].w));
        outb[(y0 + d) * 256 + t] = o;
        lmin = fminf(lmin, fminf(fminf(o.x, o.y), fminf(o.z, o.w)));
        lmax = fmaxf(lmax, fmaxf(fmaxf(o.x, o.y), fmaxf(o.z, o.w)));
    }
    for (int off = 32; off > 0; off >>= 1) {
        lmin = fminf(lmin, __shfl_down(lmin, off));
        lmax = fmaxf(lmax, __shfl_down(lmax, off));
    }
    if ((t & 63) == 0) { smin[t >> 6] = lmin; smax[t >> 6] = lmax; }
    __syncthreads();
    if (t == 0) {
        float m0 = fminf(fminf(smin[0], smin[1]), fminf(smin[2], smin[3]));
        float m1 = fmaxf(fmaxf(smax[0], smax[1]), fmaxf(smax[2], smax[3]));
        *mmslot = make_float2(m0, m1);
    }
}

// exact binarize threshold: smallest float B with (B-mn)/denom >= 0.5;
// v >= B is then bitwise identical to the reference predicate for every v.
__device__ __forceinline__ float calc_thr(float mn, float mx) {
    float denom = (mx - mn) + 1e-10f;   // reference association order
    uint32_t lo = 0, hi = 0x7F800000u;
    while (lo < hi) {
        uint32_t mid = (lo + hi) >> 1;
        float q = (__uint_as_float(mid) - mn) / denom;  // IEEE f32 div
        if (q >= 0.5f) hi = mid; else lo = mid + 1;
    }
    return __uint_as_float(lo);
}

// ---------------- LDS union-find (wave-private region) ----------------------
__device__ __forceinline__ uint32_t lload(uint32_t* lp, uint32_t x) {
    return __hip_atomic_load(&lp[x], __ATOMIC_RELAXED, __HIP_MEMORY_SCOPE_WORKGROUP);
}
__device__ __forceinline__ uint32_t lfind(uint32_t* lp, uint32_t x) {
    uint32_t p = lload(lp, x);
    while (p != x) {
        uint32_t gp = lload(lp, p);
        if (gp != p)
            __hip_atomic_store(&lp[x], gp, __ATOMIC_RELAXED, __HIP_MEMORY_SCOPE_WORKGROUP);
        x = p; p = gp;
    }
    return x;
}
__device__ uint32_t lunion(uint32_t* lp, uint32_t a, uint32_t b) {
    uint32_t ra = lfind(lp, a), rb = lfind(lp, b);
    while (ra != rb) {
        uint32_t hi = ra > rb ? ra : rb;
        uint32_t lo = ra ^ rb ^ hi;
        uint32_t old = atomicCAS(&lp[lo], lo, hi);
        if (old == lo) return 1;  // killed exactly one root
        ra = lfind(lp, old);
        rb = lfind(lp, hi);
    }
    return 0;
}
__device__ __forceinline__ int run_len(uint32_t bits) {  // consecutive 1s from bit 0
    return (int)__builtin_ctzll(~(uint64_t)bits);
}

// ---- binarize + tile-local run CCL + compact border-node emit --------------
// RUN-index labels (row*16+run#): 512-entry LP/SM. Descriptor / parent-init /
// zt stores are AGENT scope (read by other blocks within the fused kernel);
// own-tile descriptor also kept in LDS (ownd) for phase-B local reads.
__device__ void do_ccl_tile(const float* __restrict__ opened, uint8_t* __restrict__ desc,
                            uint32_t* __restrict__ parent, uint32_t* __restrict__ zt,
                            int bank, int tile, int L,
                            uint32_t* M, uint32_t* LP, uint32_t* SM,
                            float thr, uint32_t* pkslot, uint16_t* ownd) {
    int b  = tile >> 10;
    int tt = tile & 1023;
    int ty0 = (tt >> 5) << 5;
    int tx0 = (tt & 31) << 5;
    uint32_t base = (uint32_t)b * HW + (uint32_t)ty0 * WW + tx0;

    #pragma unroll
    for (int q = 0; q < 2; q++) {          // 512-entry LP/SM: 128 uint4 each
        uint32_t u = (uint32_t)L + 64u * q;
        ((uint4*)LP)[u] = make_uint4(4*u, 4*u+1, 4*u+2, 4*u+3);
        ((uint4*)SM)[u] = make_uint4(INVALID, INVALID, INVALID, INVALID);
    }

    // dense loads: lane L covers row (L>>3)+8q, cols (L&7)*4..+3
    int r8 = L >> 3, c8 = (L & 7) << 2;
    uint32_t fgcnt = 0;
    #pragma unroll
    for (int q = 0; q < 4; q++) {
        int rr = r8 + 8 * q;
        float4 v = *(const float4*)(opened + base + (uint32_t)rr * WW + c8);
        uint32_t pb = (v.x >= thr ? 1u : 0u) | (v.y >= thr ? 2u : 0u)
                    | (v.z >= thr ? 4u : 0u) | (v.w >= thr ? 8u : 0u);
        fgcnt += __popc(pb);
        uint32_t part = pb << c8;
        part |= __shfl_xor(part, 1, 8);
        part |= __shfl_xor(part, 2, 8);
        part |= __shfl_xor(part, 4, 8);
        if ((L & 7) == 0) M[rr] = part;
    }
    __syncthreads();

    // unions: lane owns half-row (r = L>>1, half h = L&1)
    int r = L >> 1, h = L & 1;
    uint32_t rowm = M[r];
    uint32_t fstarts = rowm & ~(rowm << 1);        // full-row run starts
    uint32_t halfsel = 0xFFFFu << (16 * h);
    uint32_t starts = fstarts & halfsel;
    uint32_t runs = __popc(starts);
    uint32_t links = 0;
    if (r > 0 && starts) {
        uint32_t up = M[r - 1];
        uint32_t upstarts = up & ~(up << 1);
        uint32_t w0 = starts;
        while (w0) {
            int lx = __builtin_ctz(w0); w0 &= w0 - 1;
            int e = lx + run_len(rowm >> lx) - 1;
            int lo = lx ? lx - 1 : 0;
            int hi = (e >= 31) ? 31 : e + 1;
            uint32_t hm = (hi == 31) ? 0xFFFFFFFFu : ((1u << (hi + 1)) - 1u);
            uint32_t w = up & hm & ~((1u << lo) - 1u);
            uint32_t repA = ((uint32_t)r << 4) + __popc(fstarts & ((2u << e) - 1u)) - 1u;
            while (w) {
                int xs = __builtin_ctz(w);
                int xe = xs + run_len(up >> xs) - 1;
                uint32_t repB = (((uint32_t)r - 1) << 4)
                              + __popc(upstarts & ((2u << xe) - 1u)) - 1u;
                links += lunion(LP, repA, repB);
                w = (xe >= 31) ? 0u : (w & ~((1u << (xe + 1)) - 1u));
            }
        }
    }
    __syncthreads();

    // pixel-0 / label-0: isolated fg singleton at pixel 0 (all nbrs intra-tile)
    if (tile == 0 && L == 0)
        astore32(&zt[bank], ((rowm & 1u) && !(rowm & 2u) && LP[0] == 0u) ? 1u : 0u);

    // border slot assignment: lane handles positions 2L, 2L+1
    uint32_t rk[2]; bool fgk[2];
    #pragma unroll
    for (int j = 0; j < 2; j++) {
        int k = 2 * L + j;
        int li = (k < 32) ? k
               : (k < 64) ? (31 * 32 + (k - 32))
               : (k < 96) ? ((k - 64) << 5)
                          : (((k - 96) << 5) + 31);
        int ly = li >> 5, lx = li & 31;
        uint32_t rm = M[ly];
        bool f = (rm >> lx) & 1u;
        fgk[j] = f;
        if (f) {
            int e = lx + run_len(rm >> lx) - 1;
            uint32_t rst = rm & ~(rm << 1);
            uint32_t lbl = ((uint32_t)ly << 4) + __popc(rst & ((2u << e) - 1u)) - 1u;
            rk[j] = lfind(LP, lbl);
            atomicMin(&SM[rk[j]], (uint32_t)k);
        }
    }
    __syncthreads();

    uint32_t nodebase = (uint32_t)tile << 7;
    uint32_t d2 = 0;
    #pragma unroll
    for (int j = 0; j < 2; j++) {
        int k = 2 * L + j;
        uint32_t sb = 0xFFu;
        if (fgk[j]) {
            uint32_t s = SM[rk[j]];
            sb = s;
            if (s == (uint32_t)k)
                astore32(&parent[nodebase + k], nodebase + k);  // canonical only (agent)
        }
        d2 |= sb << (8 * j);
    }
    ownd[L] = (uint16_t)d2;                              // own-tile LDS copy
    uint32_t w2 = d2 | (__shfl_down(d2, 1) << 16);
    if ((L & 1) == 0)                                    // agent u32 desc store
        astore32((uint32_t*)desc + (((uint32_t)tile) << 5) + (L >> 1), w2);

    uint32_t pk = (fgcnt << 20) | (runs << 10) | links;
    for (int off = 32; off > 0; off >>= 1) pk += __shfl_down(pk, off);
    if (L == 0) *pkslot = pk;
    __syncthreads();
}

// ---------------- global union-find on compact nodes (device scope) ---------
__device__ __forceinline__ uint32_t pload(uint32_t* P, uint32_t x) {
    return __hip_atomic_load(&P[x], __ATOMIC_RELAXED, __HIP_MEMORY_SCOPE_AGENT);
}
__device__ __forceinline__ uint32_t uf_find(uint32_t* P, uint32_t x) {
    uint32_t p = pload(P, x);
    while (p != x) {
        uint32_t gp = pload(P, p);
        if (gp != p)
            __hip_atomic_store(&P[x], gp, __ATOMIC_RELAXED, __HIP_MEMORY_SCOPE_AGENT);
        x = p; p = gp;
    }
    return x;
}
__device__ uint32_t uf_union(uint32_t* P, uint32_t a, uint32_t b) {
    uint32_t ra = uf_find(P, a);
    uint32_t rb = uf_find(P, b);
    while (ra != rb) {
        uint32_t hi = ra > rb ? ra : rb;
        uint32_t lo = ra ^ rb ^ hi;
        uint32_t old = atomicCAS(&P[lo], lo, hi);
        if (old == lo) return 1;  // killed exactly one root
        ra = uf_find(P, old);
        rb = uf_find(P, hi);
    }
    return 0;
}

// ---------------- kernels ---------------------------------------------------
__global__ void k_open2(const float* __restrict__ img, const float* __restrict__ lab,
                        float* __restrict__ op0, float* __restrict__ op1,
                        float2* __restrict__ mm, uint32_t* __restrict__ zt,
                        uint32_t* __restrict__ gct) {
    __shared__ uint32_t S[5168];
    if (blockIdx.x == 0) {
        if (threadIdx.x < 64) astore32(&gct[threadIdx.x], 0u);   // group tickets
        if (threadIdx.x == 0) {
            astore32(&zt[2], 0u);    // top ticket (kernel boundary = visible)
            uint32_t n = __hip_atomic_fetch_add(&zt[3], 1u,
                                                __ATOMIC_RELAXED, __HIP_MEMORY_SCOPE_AGENT);
            astore32(&zt[4], n);     // iteration nonce for claim tags
        }
    }
    int bank = blockIdx.x >> 9;
    do_open_strip(bank ? lab : img, bank ? op1 : op0,
                  blockIdx.x & 511, S, &mm[blockIdx.x]);
}

// Fused CCL + border (r8-verified seam partition & claim protocol).
__global__ __launch_bounds__(256, 8) void k_cclb(
        const float* __restrict__ op0, const float* __restrict__ op1,
        uint8_t* __restrict__ d0, uint8_t* __restrict__ d1,
        uint32_t* __restrict__ p0, uint32_t* __restrict__ p1,
        const float2* __restrict__ mm,
        unsigned long long* __restrict__ fcs, uint32_t* __restrict__ lks,
        unsigned long long* __restrict__ cw, uint32_t* __restrict__ zt,
        uint32_t* __restrict__ gct, float* __restrict__ out) {
    __shared__ __align__(16) uint32_t S[4240];
    __shared__ uint16_t ownd[4][64];
    __shared__ uint32_t wonA[8], slist[16], clist[16], nsc2[2], qn;
    __shared__ uint32_t SWK[6];
    __shared__ unsigned long long SB[8];
    __shared__ uint32_t SL[8];

    int bank = blockIdx.x >> 10;
    int wave = threadIdx.x >> 6, L = threadIdx.x & 63;
    uint8_t* desc = bank ? d1 : d0;
    uint32_t* parent = bank ? p1 : p0;
    uint32_t tb4 = blockIdx.x & 1023u;   // per-bank block id

    // per-bank min/max from the 512 strip slots (kernel boundary vs k_open2)
    {
        const float2* mb = mm + (bank << 9);
        float2 u = mb[threadIdx.x];
        float2 v = mb[threadIdx.x + 256];
        float mn = fminf(u.x, v.x), mx = fmaxf(u.y, v.y);
        for (int off = 32; off > 0; off >>= 1) {
            mn = fminf(mn, __shfl_down(mn, off));
            mx = fmaxf(mx, __shfl_down(mx, off));
        }
        float* sf = (float*)(S + 4228);
        if (L == 0) { sf[wave] = mn; sf[4 + wave] = mx; }
    }
    __syncthreads();
    float* sf = (float*)(S + 4228);
    float mnA = fminf(fminf(sf[0], sf[1]), fminf(sf[2], sf[3]));
    float mxA = fmaxf(fmaxf(sf[4], sf[5]), fmaxf(sf[6], sf[7]));
    float thr = calc_thr(mnA, mxA);

    // ---- phase A: tile CCL (verified core) ----
    uint32_t* M = S + wave * 1056;    // M[32] | LP[512] | SM[512]
    int tile = ((blockIdx.x & 1023) << 2) + wave;
    do_ccl_tile(bank ? op1 : op0, desc, parent, zt, bank,
                tile, L, M, M + 32, M + 544, thr, &S[4224 + wave], ownd[wave]);
    if (threadIdx.x == 0) {
        uint32_t fg = 0, comp = 0;
        #pragma unroll
        for (int w = 0; w < 4; w++) {
            uint32_t pk = S[4224 + w];
            fg   += pk >> 20;
            comp += ((pk >> 10) & 1023u) - (pk & 1023u);
        }
        __hip_atomic_store(&fcs[blockIdx.x],
                           ((unsigned long long)comp << 32) | fg,
                           __ATOMIC_RELAXED, __HIP_MEMORY_SCOPE_AGENT);
    }

    // ---- wait-free pairwise claims (threads 0..7: 4 forward, 4 backward) ---
    if (threadIdx.x < 8) {
        int j = threadIdx.x & 3;
        bool fw = threadIdx.x < 4;
        int k = (j == 0) ? 1 : (j == 1) ? 7 : (j == 2) ? 8 : 9;
        long long A = fw ? (long long)blockIdx.x : (long long)blockIdx.x - k;
        uint32_t won = 0xFFFFFFFFu;
        if (A >= 0) {
            uint32_t Ar = (uint32_t)A;
            uint32_t a255 = Ar & 255u, a7 = Ar & 7u;
            bool valid = (k == 1) ? (a7 != 7u)
                       : (k == 7) ? ((a255 < 248u) && (a7 != 0u))
                       : (k == 8) ? (a255 < 248u)
                                  : ((a255 < 248u) && (a7 != 7u));
            if (valid) {
                uint32_t nonce = aload32(&zt[4]);
                uint32_t word = Ar * 4u + (uint32_t)j;
                unsigned long long my = ctag(word, fw ? 0u : 1u, nonce);
                unsigned long long ot = ctag(word, fw ? 1u : 0u, nonce);
                unsigned long long old = __hip_atomic_exchange(&cw[word], my,
                        __ATOMIC_RELAXED, __HIP_MEMORY_SCOPE_AGENT);
                if (old == ot) won = Ar;   // second arriver: both descs published
            }
        }
        wonA[threadIdx.x] = won;
    }
    if (threadIdx.x == 200) qn = 0;
    __syncthreads();

    // ---- build seam/corner work lists (thread 0; tiny) ----
    if (threadIdx.x == 0) {
        int ns = 0, nc = 0;
        uint32_t tb = tb4 << 2;
        slist[ns++] = tb + 0;              // intra E seams (txx<31 always)
        slist[ns++] = tb + 1;
        slist[ns++] = tb + 2;
        #pragma unroll
        for (int s = 0; s < 8; s++) {
            uint32_t A = wonA[s];
            if (A == 0xFFFFFFFFu) continue;
            uint32_t at = (A & 1023u) << 2;
            int j = s & 3;
            if (j == 0) slist[ns++] = at + 3;                              // k=1: E
            else if (j == 2) {                                             // k=8
                slist[ns++] = (at + 0) | 0x1000u;
                slist[ns++] = (at + 1) | 0x1000u;
                slist[ns++] = (at + 2) | 0x1000u;
                slist[ns++] = (at + 3) | 0x1000u;
                clist[nc++] = at + 0;  clist[nc++] = at + 1;  clist[nc++] = at + 2;   // SE
                clist[nc++] = (at + 1) | 0x1000u;  clist[nc++] = (at + 2) | 0x1000u;  // SW
                clist[nc++] = (at + 3) | 0x1000u;
            }
            else if (j == 3) clist[nc++] = at + 3;                         // k=9: SE
            else clist[nc++] = at | 0x1000u;                               // k=7: SW
        }
        nsc2[0] = (uint32_t)ns; nsc2[1] = (uint32_t)nc;
    }
    __syncthreads();

    // ---- phase B: seam pair-gen (verified dedup), queue in reused S ----
    unsigned long long* Q = (unsigned long long*)S;   // <=1264 pairs, 2120 cap
    uint32_t ns = nsc2[0], nc = nsc2[1];
    const uint32_t* d32 = (const uint32_t*)desc;
    for (uint32_t s0 = 0; s0 < ns; s0 += 8) {
        uint32_t s = s0 + (threadIdx.x >> 5);
        int x = threadIdx.x & 31;
        uint32_t sA = 0xFFu, t = 0xFFu, nQ = 0, nP = 0;
        bool act = (s < ns);
        if (act) {
            uint32_t e = slist[s];
            uint32_t Qt = e & 4095u;
            bool row = (e & 0x1000u) != 0;
            uint32_t Pt = row ? (Qt + 32u) : (Qt + 1u);
            nQ = Qt << 7; nP = Pt << 7;
            sA = read_desc_b(d32, ownd, tb4, Qt, row ? (32u + (uint32_t)x) : (96u + (uint32_t)x));
            t  = read_desc_b(d32, ownd, tb4, Pt, row ? (uint32_t)x : (64u + (uint32_t)x));
        }
        uint32_t tp1  = __shfl(t,  L + 1);
        uint32_t tm1  = __shfl(t,  L - 1);
        uint32_t sAp1 = __shfl(sA, L + 1);
        uint32_t sAm1 = __shfl(sA, L - 1);
        if (act && sA != 0xFFu) {
            uint32_t a = nQ + sA;
            if (t != 0xFFu && !(x > 0 && sAm1 == sA && tm1 == t))
                Q[atomicAdd(&qn, 1u)] = ((unsigned long long)a << 32) | (nP + t);
            if (x < 31 && tp1 != 0xFFu && tp1 != t && sAp1 != sA)
                Q[atomicAdd(&qn, 1u)] = ((unsigned long long)a << 32) | (nP + tp1);
            if (x > 0 && tm1 != 0xFFu && tm1 != t && sAm1 != sA)
                Q[atomicAdd(&qn, 1u)] = ((unsigned long long)a << 32) | (nP + tm1);
        }
    }
    if (threadIdx.x < nc) {
        uint32_t e = clist[threadIdx.x];
        uint32_t Qt = e & 4095u;
        bool isSW = (e & 0x1000u) != 0;
        uint32_t Pt = isSW ? (Qt + 31u) : (Qt + 33u);
        uint32_t sB = read_desc_b(d32, ownd, tb4, Qt, isSW ? 32u : 63u);   // dQ[32]/dQ[63]
        uint32_t sQ = read_desc_b(d32, ownd, tb4, Pt, isSW ? 31u : 0u);    // dP[31]/dP[0]
        if (sB != 0xFFu && sQ != 0xFFu)
            Q[atomicAdd(&qn, 1u)] =
                ((unsigned long long)((Qt << 7) + sB) << 32) | ((Pt << 7) + sQ);
    }
    __syncthreads();

    // ---- rebalanced union phase: all 256 threads share the queue ----
    uint32_t n = qn;
    uint32_t links = 0;
    for (uint32_t i = threadIdx.x; i < n; i += 256) {
        unsigned long long q = Q[i];
        links += uf_union(parent, (uint32_t)(q >> 32), (uint32_t)q);
    }
    for (int off = 32; off > 0; off >>= 1) links += __shfl_down(links, off);
    if (L == 0) SWK[wave] = links;
    __syncthreads();
    if (threadIdx.x == 0) {
        uint32_t lk = SWK[0] + SWK[1] + SWK[2] + SWK[3];
        __hip_atomic_store(&lks[blockIdx.x], lk, __ATOMIC_RELAXED, __HIP_MEMORY_SCOPE_AGENT);
        asm volatile("s_waitcnt vmcnt(0)" ::: "memory");   // r3-proven pattern
        // hierarchical ticket: 64 groups x 32 blocks, then a 64-deep top.
        // Same store->drain->RMW-chain visibility argument applied twice.
        uint32_t go = __hip_atomic_fetch_add(&gct[blockIdx.x >> 5], 1u,
                                             __ATOMIC_RELAXED, __HIP_MEMORY_SCOPE_AGENT);
        uint32_t last = 0;
        if (go == 31u) {
            uint32_t to = __hip_atomic_fetch_add(&zt[2], 1u,
                                                 __ATOMIC_RELAXED, __HIP_MEMORY_SCOPE_AGENT);
            last = (to == 63u) ? 1u : 0u;
        }
        SWK[4] = last;
    }
    __syncthreads();
    if (SWK[4]) {   // last of 2048 blocks: fused final reduce
        unsigned long long a0 = 0, a1 = 0;
        uint32_t l0 = 0, l1 = 0;
        #pragma unroll
        for (int k = 0; k < 4; k++) {
            int i = (int)threadIdx.x + (k << 8);
            a0 += __hip_atomic_load(&fcs[i],        __ATOMIC_RELAXED, __HIP_MEMORY_SCOPE_AGENT);
            a1 += __hip_atomic_load(&fcs[1024 + i], __ATOMIC_RELAXED, __HIP_MEMORY_SCOPE_AGENT);
            l0 += aload32(&lks[i]);
            l1 += aload32(&lks[1024 + i]);
        }
        for (int off = 32; off > 0; off >>= 1) {
            a0 += __shfl_down(a0, off);
            a1 += __shfl_down(a1, off);
            l0 += __shfl_down(l0, off);
            l1 += __shfl_down(l1, off);
        }
        if (L == 0) { SB[wave] = a0; SB[4 + wave] = a1; SL[wave] = l0; SL[4 + wave] = l1; }
        __syncthreads();
        if (threadIdx.x == 0) {
            unsigned long long A0 = SB[0] + SB[1] + SB[2] + SB[3];
            unsigned long long A1 = SB[4] + SB[5] + SB[6] + SB[7];
            uint32_t gl0 = SL[0] + SL[1] + SL[2] + SL[3];
            uint32_t gl1 = SL[4] + SL[5] + SL[6] + SL[7];
            uint32_t nf0 = (uint32_t)A0, lc0 = (uint32_t)(A0 >> 32);
            uint32_t nf1 = (uint32_t)A1, lc1 = (uint32_t)(A1 >> 32);
            uint32_t z0 = aload32(&zt[0]);
            uint32_t z1 = aload32(&zt[1]);
            uint32_t comps0 = lc0 - gl0;
            uint32_t comps1 = lc1 - gl1;
            float ccs  = (float)(comps0 - z0 + ((nf0 < (uint32_t)NPIX || z0) ? 1u : 0u));
            float ccsg = (float)(comps1 - z1 + ((nf1 < (uint32_t)NPIX || z1) ? 1u : 0u));
            out[0] = fabsf(ccsg - ccs) / (float)nf1;   // all exact ints < 2^24
        }
    }
}

extern "C" void kernel_launch(void* const* d_in, const int* in_sizes, int n_in,
                              void* d_out, int out_size, void* d_ws, size_t ws_size,
                              hipStream_t stream) {
    const float* img = (const float*)d_in[0];
    const float* lab = (const float*)d_in[1];
    float* out = (float*)d_out;
    char* ws = (char*)d_ws;

    float*    op0 = (float*)ws;                                      // 16 MB
    float*    op1 = (float*)(ws + (size_t)16 * 1024 * 1024);         // 16 MB
    uint8_t*  d0  = (uint8_t*)(ws + (size_t)32 * 1024 * 1024);       // 512 KB
    uint8_t*  d1  = (uint8_t*)(ws + (size_t)32 * 1024 * 1024 + 512 * 1024);
    uint32_t* p0  = (uint32_t*)(ws + (size_t)33 * 1024 * 1024);      // 2 MB
    uint32_t* p1  = (uint32_t*)(ws + (size_t)35 * 1024 * 1024);      // 2 MB
    char*     aux = ws + (size_t)37 * 1024 * 1024;
    float2*   mm  = (float2*)aux;                                    // 8 KB
    unsigned long long* fcs = (unsigned long long*)(aux + 8192);     // 16 KB
    uint32_t* lks = (uint32_t*)(aux + 24576);                        // 8 KB
    uint32_t* zt  = (uint32_t*)(aux + 32768);                        // 32 B
    uint32_t* gct = (uint32_t*)(aux + 33024);                        // 256 B
    unsigned long long* cw  = (unsigned long long*)(aux + 40960);    // 64 KB

    k_open2<<<2 * NB * (HH / RS), 256, 0, stream>>>(img, lab, op0, op1, mm, zt, gct);
    k_cclb<<<2 * NT / 4, 256, 0, stream>>>(op0, op1, d0, d1, p0, p1, mm,
                                           fcs, lks, cw, zt, gct, out);
}